// Round 1
// baseline (1486.492 us; speedup 1.0000x reference)
//
#include <hip/hip_runtime.h>
#include <math.h>

#define TT 4096
#define U  32

// 16-term dot, 4-way split accumulation (float[16] · float[16])
__device__ __forceinline__ float dot16f(const float* a, const float* w) {
    float p0 = a[0]*w[0], p1 = a[1]*w[1], p2 = a[2]*w[2], p3 = a[3]*w[3];
    p0 = fmaf(a[4],  w[4],  p0); p1 = fmaf(a[5],  w[5],  p1);
    p2 = fmaf(a[6],  w[6],  p2); p3 = fmaf(a[7],  w[7],  p3);
    p0 = fmaf(a[8],  w[8],  p0); p1 = fmaf(a[9],  w[9],  p1);
    p2 = fmaf(a[10], w[10], p2); p3 = fmaf(a[11], w[11], p3);
    p0 = fmaf(a[12], w[12], p0); p1 = fmaf(a[13], w[13], p1);
    p2 = fmaf(a[14], w[14], p2); p3 = fmaf(a[15], w[15], p3);
    return (p0+p1)+(p2+p3);
}

// 16-term dot from 4x float4
__device__ __forceinline__ float dot16v(const float4* xq, const float* w) {
    float p0 = xq[0].x*w[0], p1 = xq[0].y*w[1], p2 = xq[0].z*w[2], p3 = xq[0].w*w[3];
    p0 = fmaf(xq[1].x, w[4],  p0); p1 = fmaf(xq[1].y, w[5],  p1);
    p2 = fmaf(xq[1].z, w[6],  p2); p3 = fmaf(xq[1].w, w[7],  p3);
    p0 = fmaf(xq[2].x, w[8],  p0); p1 = fmaf(xq[2].y, w[9],  p1);
    p2 = fmaf(xq[2].z, w[10], p2); p3 = fmaf(xq[2].w, w[11], p3);
    p0 = fmaf(xq[3].x, w[12], p0); p1 = fmaf(xq[3].y, w[13], p1);
    p2 = fmaf(xq[3].z, w[14], p2); p3 = fmaf(xq[3].w, w[15], p3);
    return (p0+p1)+(p2+p3);
}

__global__ __launch_bounds__(64, 1)
void rnn_fused(const float* __restrict__ x,  const float* __restrict__ W1,
               const float* __restrict__ b1, const float* __restrict__ W2,
               const float* __restrict__ b2, const float* __restrict__ Wc,
               const float* __restrict__ bc, float* __restrict__ out, int B)
{
    const int lane = threadIdx.x & 63;
    const int v    = lane & 31;        // output unit
    const int kh   = lane >> 5;        // k-half (0: u=0..15, 1: u=16..31)
    const int b    = blockIdx.x;
    if (b >= B) return;

    // Weight columns in registers: w1[i] = W1[kh*16+i][v], w2[i] = W2[kh*16+i][v]
    float w1[16], w2[16];
    #pragma unroll
    for (int i = 0; i < 16; ++i) {
        w1[i] = W1[(kh*16 + i)*U + v];
        w2[i] = W2[(kh*16 + i)*U + v];
    }
    const float b1v = b1[v], b2v = b2[v];

    // this lane's half-row base: x[b][t][kh*16 .. kh*16+15]
    const float* xrow = x + (size_t)b * TT * U + kh*16;

    // double-buffered x registers: 4 timesteps x 4 float4 each
    float4 xa[4][4], xb[4][4];
    #pragma unroll
    for (int s = 0; s < 4; ++s) {
        const float4* src = (const float4*)(xrow + (size_t)s * U);
        #pragma unroll
        for (int q = 0; q < 4; ++q) xa[s][q] = src[q];
    }

    float state = 0.f;   // y_{t-1}, replicated in both k-halves
    float pool  = 0.f;   // sum over t of y_t[v]

    // process 4 timesteps using xc, prefetch the next 4 into xn
    auto quad = [&](const float4 (&xc)[4][4], float4 (&xn)[4][4], int t0) {
        int tp = t0 + 4;
        if (tp + 4 > TT) tp = 0;       // harmless dummy prefetch on last chunk
        #pragma unroll
        for (int s = 0; s < 4; ++s) {
            const float4* src = (const float4*)(xrow + (size_t)(tp + s) * U);
            #pragma unroll
            for (int q = 0; q < 4; ++q) xn[s][q] = src[q];
        }
        #pragma unroll
        for (int s = 0; s < 4; ++s) {
            // --- serial chain: broadcast state, half-dot with W2 ---
            float sb[16];
            #pragma unroll
            for (int i = 0; i < 16; ++i) sb[i] = __shfl(state, kh*16 + i);
            float z = dot16f(sb, w2);
            z += __shfl_xor(z, 32);                 // combine k-halves
            float h = tanhf(z + b2v);
            // --- off-chain: input projection for this step ---
            float p = dot16v(xc[s], w1);
            p += __shfl_xor(p, 32);
            float px = tanhf(p + b1v);
            // --- update ---
            state = px + h;
            pool += state;
        }
    };

    for (int c = 0; c < TT/8; ++c) {
        quad(xa, xb, c*8);
        quad(xb, xa, c*8 + 4);
    }

    // out[b] = (pool/T) . Wc + bc   (pool replicated across halves; reduce within 32)
    float r = pool * Wc[v];
    r += __shfl_xor(r, 16);
    r += __shfl_xor(r, 8);
    r += __shfl_xor(r, 4);
    r += __shfl_xor(r, 2);
    r += __shfl_xor(r, 1);
    if (lane == 0) out[b] = r * (1.0f / TT) + bc[0];
}

extern "C" void kernel_launch(void* const* d_in, const int* in_sizes, int n_in,
                              void* d_out, int out_size, void* d_ws, size_t ws_size,
                              hipStream_t stream) {
    const float* x  = (const float*)d_in[0];
    const float* W1 = (const float*)d_in[1];
    const float* b1 = (const float*)d_in[2];
    const float* W2 = (const float*)d_in[3];
    const float* b2 = (const float*)d_in[4];
    const float* Wc = (const float*)d_in[5];
    const float* bc = (const float*)d_in[6];
    float* out = (float*)d_out;

    const int B = out_size;  // 256
    rnn_fused<<<B, 64, 0, stream>>>(x, W1, b1, W2, b2, Wc, bc, out, B);
}

// Round 2
// 1105.499 us; speedup vs baseline: 1.3446x; 1.3446x over previous
//
#include <hip/hip_runtime.h>
#include <math.h>

#define TT 4096
#define U  32

// branch-free fast tanh: 1 - 2/(1+e^{2x}); exp2+rcp are ~1 ulp HW ops.
__device__ __forceinline__ float tanh_fast(float x) {
    float t = __builtin_amdgcn_exp2f(x * 2.88539008177793f); // e^{2x} = 2^{2x*log2(e)}
    float r = __builtin_amdgcn_rcpf(t + 1.0f);
    return fmaf(-2.0f, r, 1.0f);
}

// 16-term dot from 4x float4 with init value, 4-way split accumulation
__device__ __forceinline__ float dot16v_b(const float4* xq, const float* w, float init) {
    float p0 = fmaf(xq[0].x, w[0], init);
    float p1 = xq[0].y * w[1];
    float p2 = xq[0].z * w[2];
    float p3 = xq[0].w * w[3];
    p0 = fmaf(xq[1].x, w[4],  p0); p1 = fmaf(xq[1].y, w[5],  p1);
    p2 = fmaf(xq[1].z, w[6],  p2); p3 = fmaf(xq[1].w, w[7],  p3);
    p0 = fmaf(xq[2].x, w[8],  p0); p1 = fmaf(xq[2].y, w[9],  p1);
    p2 = fmaf(xq[2].z, w[10], p2); p3 = fmaf(xq[2].w, w[11], p3);
    p0 = fmaf(xq[3].x, w[12], p0); p1 = fmaf(xq[3].y, w[13], p1);
    p2 = fmaf(xq[3].z, w[14], p2); p3 = fmaf(xq[3].w, w[15], p3);
    return (p0 + p1) + (p2 + p3);
}

__global__ __launch_bounds__(64, 1)
void rnn_fused(const float* __restrict__ x,  const float* __restrict__ W1,
               const float* __restrict__ b1, const float* __restrict__ W2,
               const float* __restrict__ b2, const float* __restrict__ Wc,
               const float* __restrict__ bc, float* __restrict__ out, int B)
{
    const int lane = threadIdx.x & 63;
    const int v    = lane & 31;        // output unit (replicated across halves)
    const int kh   = lane >> 5;        // k-half for the px dot only
    const int b    = blockIdx.x;
    if (b >= B) return;

    // px weights: w1[i] = W1[kh*16+i][v]  (k-split halves, combined via shfl_xor)
    float w1[16];
    #pragma unroll
    for (int i = 0; i < 16; ++i) w1[i] = W1[(kh*16 + i)*U + v];

    // z weights: full column, w2[i] = W2[i][v]  (no k-split -> no cross-lane on chain)
    float w2[32];
    #pragma unroll
    for (int i = 0; i < 32; ++i) w2[i] = W2[i*U + v];

    const float b2v = b2[v];
    const float b1h = 0.5f * b1[v];    // halved: both k-halves add it, sums to b1[v]

    // this lane's half-row base: x[b][t][kh*16 .. kh*16+15]
    const float* xrow = x + (size_t)b * TT * U + kh*16;

    // double-buffered x registers: 4 timesteps x 4 float4 (16 floats = half row)
    float4 xa[4][4], xb[4][4];
    #pragma unroll
    for (int s = 0; s < 4; ++s) {
        const float4* src = (const float4*)(xrow + (size_t)s * U);
        #pragma unroll
        for (int q = 0; q < 4; ++q) xa[s][q] = src[q];
    }

    float state = 0.f;   // y_{t-1}[v], replicated in both halves
    float pool  = 0.f;   // sum over t of y_t[v]

    auto quad = [&](const float4 (&xc)[4][4], float4 (&xn)[4][4], int t0) {
        // prefetch next quad
        int tp = t0 + 4;
        if (tp + 4 > TT) tp = 0;       // harmless dummy prefetch on last chunk
        #pragma unroll
        for (int s = 0; s < 4; ++s) {
            const float4* src = (const float4*)(xrow + (size_t)(tp + s) * U);
            #pragma unroll
            for (int q = 0; q < 4; ++q) xn[s][q] = src[q];
        }

        // ---- off-chain block: px for all 4 steps, hoisted ahead of the chain ----
        float px[4];
        #pragma unroll
        for (int s = 0; s < 4; ++s) {
            float p = dot16v_b(xc[s], w1, b1h);
            p += __shfl_xor(p, 32);            // combine k-halves (off critical path)
            px[s] = tanh_fast(p);
        }

        // ---- serial chain: 4 steps of state -> readlane bcast -> dot32 -> tanh ----
        #pragma unroll
        for (int s = 0; s < 4; ++s) {
            float a0 = b2v, a1 = 0.f, a2 = 0.f, a3 = 0.f;
            #pragma unroll
            for (int i = 0; i < 32; i += 4) {
                float s0 = __int_as_float(__builtin_amdgcn_readlane(__float_as_int(state), i+0));
                float s1 = __int_as_float(__builtin_amdgcn_readlane(__float_as_int(state), i+1));
                float s2 = __int_as_float(__builtin_amdgcn_readlane(__float_as_int(state), i+2));
                float s3 = __int_as_float(__builtin_amdgcn_readlane(__float_as_int(state), i+3));
                a0 = fmaf(s0, w2[i+0], a0);
                a1 = fmaf(s1, w2[i+1], a1);
                a2 = fmaf(s2, w2[i+2], a2);
                a3 = fmaf(s3, w2[i+3], a3);
            }
            float z = (a0 + a1) + (a2 + a3);
            float h = tanh_fast(z);
            state = px[s] + h;
            pool += state;
        }
    };

    for (int c = 0; c < TT/8; ++c) {
        quad(xa, xb, c*8);
        quad(xb, xa, c*8 + 4);
    }

    // out[b] = (pool/T) . Wc + bc   (pool replicated across halves; reduce within 32)
    float r = pool * Wc[v];
    r += __shfl_xor(r, 16);
    r += __shfl_xor(r, 8);
    r += __shfl_xor(r, 4);
    r += __shfl_xor(r, 2);
    r += __shfl_xor(r, 1);
    if (lane == 0) out[b] = r * (1.0f / TT) + bc[0];
}

extern "C" void kernel_launch(void* const* d_in, const int* in_sizes, int n_in,
                              void* d_out, int out_size, void* d_ws, size_t ws_size,
                              hipStream_t stream) {
    const float* x  = (const float*)d_in[0];
    const float* W1 = (const float*)d_in[1];
    const float* b1 = (const float*)d_in[2];
    const float* W2 = (const float*)d_in[3];
    const float* b2 = (const float*)d_in[4];
    const float* Wc = (const float*)d_in[5];
    const float* bc = (const float*)d_in[6];
    float* out = (float*)d_out;

    const int B = out_size;  // 256
    rnn_fused<<<B, 64, 0, stream>>>(x, W1, b1, W2, b2, Wc, bc, out, B);
}

// Round 3
// 808.832 us; speedup vs baseline: 1.8378x; 1.3668x over previous
//
#include <hip/hip_runtime.h>

#define TT  4096
#define U   32
#define CH  32              // timesteps per LDS chunk
#define NCH (TT/CH)         // 128 chunks

// branch-free fast tanh: 1 - 2/(1+e^{2x}); exp2+rcp are ~1 ulp HW ops.
__device__ __forceinline__ float tanh_fast(float x) {
    float t = __builtin_amdgcn_exp2f(x * 2.88539008177793f);
    float r = __builtin_amdgcn_rcpf(t + 1.0f);
    return fmaf(-2.0f, r, 1.0f);
}

__device__ __forceinline__ float rl(float s, int l) {
    return __uint_as_float(__builtin_amdgcn_readlane(__float_as_uint(s), l));
}

__global__ __launch_bounds__(64, 1)
void rnn_fused(const float* __restrict__ x,  const float* __restrict__ W1,
               const float* __restrict__ b1, const float* __restrict__ W2,
               const float* __restrict__ b2, const float* __restrict__ Wc,
               const float* __restrict__ bc, float* __restrict__ out, int B)
{
    __shared__ __align__(16) float lds[2*CH*U];   // 8 KB: two chunk buffers
    const int lane = threadIdx.x & 63;
    const int v    = lane & 31;        // output unit
    const int kh   = lane >> 5;        // half id: 0 -> even steps, 1 -> odd steps (for px)
    const int b    = blockIdx.x;
    if (b >= B) return;

    // full weight columns per lane
    float w1[U], w2[U];
    #pragma unroll
    for (int i = 0; i < U; ++i) { w1[i] = W1[i*U + v]; w2[i] = W2[i*U + v]; }
    const float b1v = b1[v], b2v = b2[v];

    const float* xb = x + (size_t)b * TT * U;

    // ---- stage chunk 0 into buffer 0 (async, no VGPR round-trip) ----
    #pragma unroll
    for (int q = 0; q < 4; ++q) {
        const float* src = xb + q*256 + lane*4;
        __builtin_amdgcn_global_load_lds(
            (const __attribute__((address_space(1))) void*)src,
            (__attribute__((address_space(3))) void*)(lds + q*256),
            16, 0, 0);
    }
    asm volatile("s_waitcnt vmcnt(0)" ::: "memory");
    __builtin_amdgcn_sched_barrier(0);

    // prologue: read pair-0 row (row 0+kh) into xrA (full 32-float row per lane)
    float4 xrA[8], xrB[8];
    {
        const float4* p0 = (const float4*)((const char*)lds + kh*128);
        #pragma unroll
        for (int q = 0; q < 8; ++q) xrA[q] = p0[q];
    }

    unsigned rdoff = (unsigned)((2 + kh) * 128);   // byte offset of pair-1 row for this half
    float state = 0.f, pool_e = 0.f, pool_o = 0.f;

    // one chain step: broadcast prev state via readlane (base = where y_{t-1} lives),
    // 32-FMA dot with W2 column, tanh, add px (valid in this step's half).
    auto chain = [&](float px_pair, int base, float& pool_reg) {
        float a0 = b2v, a1 = 0.f, a2 = 0.f, a3 = 0.f;
        #pragma unroll
        for (int i = 0; i < 32; i += 4) {
            float s0 = rl(state, base + i + 0);
            float s1 = rl(state, base + i + 1);
            float s2 = rl(state, base + i + 2);
            float s3 = rl(state, base + i + 3);
            a0 = fmaf(s0, w2[i+0], a0);
            a1 = fmaf(s1, w2[i+1], a1);
            a2 = fmaf(s2, w2[i+2], a2);
            a3 = fmaf(s3, w2[i+3], a3);
        }
        float z = (a0 + a1) + (a2 + a3);
        float h = tanh_fast(z);
        state = px_pair + h;
        pool_reg += state;
    };

    // full 32-term px dot from a register row
    auto pxdot = [&](const float4 (&xr)[8]) -> float {
        float a0 = b1v, a1 = 0.f, a2 = 0.f, a3 = 0.f;
        #pragma unroll
        for (int q = 0; q < 8; ++q) {
            a0 = fmaf(xr[q].x, w1[q*4+0], a0);
            a1 = fmaf(xr[q].y, w1[q*4+1], a1);
            a2 = fmaf(xr[q].z, w1[q*4+2], a2);
            a3 = fmaf(xr[q].w, w1[q*4+3], a3);
        }
        return tanh_fast((a0 + a1) + (a2 + a3));
    };

    for (int Q = 0; Q < TT/4; ++Q) {     // Q covers 4 timesteps: pairs 2Q, 2Q+1
        // ---------- sub-body 0 : pair 2Q (steps 4Q, 4Q+1) ----------
        if ((Q & 7) == 0) {
            // issue next chunk's staging loads (one chunk ~6000cy ahead of use)
            int c1   = (Q >> 3) + 1;
            int csrc = (c1 < NCH) ? c1 : (NCH - 1);     // harmless dummy on last
            const float* srcb = xb + (size_t)csrc * (CH*U);
            float*       dstb = lds + (c1 & 1) * (CH*U);
            #pragma unroll
            for (int q = 0; q < 4; ++q) {
                __builtin_amdgcn_global_load_lds(
                    (const __attribute__((address_space(1))) void*)(srcb + q*256 + lane*4),
                    (__attribute__((address_space(3))) void*)(dstb + q*256),
                    16, 0, 0);
            }
        }
        {   // ds_read rows of pair 2Q+1 -> xrB (consumed next sub-body)
            const float4* p = (const float4*)((const char*)lds + rdoff);
            #pragma unroll
            for (int q = 0; q < 8; ++q) xrB[q] = p[q];
            rdoff = (rdoff + 256u) & 8191u;
        }
        {
            float px = pxdot(xrA);       // lanes0-31: px(4Q), lanes32-63: px(4Q+1)
            chain(px, 32, pool_e);       // step 4Q   (y_{4Q-1} lives in lanes 32-63)
            chain(px,  0, pool_o);       // step 4Q+1 (y_{4Q} lives in lanes 0-31)
        }

        // ---------- sub-body 1 : pair 2Q+1 (steps 4Q+2, 4Q+3) ----------
        if ((Q & 7) == 7) {
            // next pair's rows are in the other buffer -> its loads must have landed
            asm volatile("s_waitcnt vmcnt(0)" ::: "memory");
            __builtin_amdgcn_sched_barrier(0);
        }
        {   // ds_read rows of pair 2Q+2 -> xrA
            const float4* p = (const float4*)((const char*)lds + rdoff);
            #pragma unroll
            for (int q = 0; q < 8; ++q) xrA[q] = p[q];
            rdoff = (rdoff + 256u) & 8191u;
        }
        {
            float px = pxdot(xrB);       // steps 4Q+2 / 4Q+3
            chain(px, 32, pool_e);       // step 4Q+2
            chain(px,  0, pool_o);       // step 4Q+3
        }
    }

    // epilogue: pooled[v] = sum_e (lanes0-31) + sum_o (lanes32-63)
    float po  = __shfl(pool_o, lane + 32);    // lanes0-31 pull their odd-half sum
    float tot = pool_e + po;                  // valid in lanes 0-31
    float r = tot * Wc[v];
    r += __shfl_xor(r, 16);
    r += __shfl_xor(r, 8);
    r += __shfl_xor(r, 4);
    r += __shfl_xor(r, 2);
    r += __shfl_xor(r, 1);
    if (lane == 0) out[b] = r * (1.0f / TT) + bc[0];
}

extern "C" void kernel_launch(void* const* d_in, const int* in_sizes, int n_in,
                              void* d_out, int out_size, void* d_ws, size_t ws_size,
                              hipStream_t stream) {
    const float* x  = (const float*)d_in[0];
    const float* W1 = (const float*)d_in[1];
    const float* b1 = (const float*)d_in[2];
    const float* W2 = (const float*)d_in[3];
    const float* b2 = (const float*)d_in[4];
    const float* Wc = (const float*)d_in[5];
    const float* bc = (const float*)d_in[6];
    float* out = (float*)d_out;

    const int B = out_size;  // 256
    rnn_fused<<<B, 64, 0, stream>>>(x, W1, b1, W2, b2, Wc, bc, out, B);
}

// Round 4
// 586.760 us; speedup vs baseline: 2.5334x; 1.3785x over previous
//
#include <hip/hip_runtime.h>

#define TT  4096
#define U   32
#define CH  32              // timesteps per chunk
#define NCH (TT/CH)         // 128 chunks

// branch-free fast tanh: 1 - 2/(1+e^{2x}); exp2+rcp are ~1 ulp HW ops.
__device__ __forceinline__ float tanh_fast(float x) {
    float t = __builtin_amdgcn_exp2f(x * 2.88539008177793f);
    float r = __builtin_amdgcn_rcpf(t + 1.0f);
    return fmaf(-2.0f, r, 1.0f);
}

__global__ __launch_bounds__(192, 1)
void rnn_fused(const float* __restrict__ x,  const float* __restrict__ W1,
               const float* __restrict__ b1, const float* __restrict__ W2,
               const float* __restrict__ b2, const float* __restrict__ Wc,
               const float* __restrict__ bc, float* __restrict__ out, int B)
{
    // [slot][batch][t][u] rings + 64-float state-broadcast scratch
    __shared__ __align__(16) float xring[2][2][CH][U];   // 16 KB
    __shared__ __align__(16) float pxring[2][2][CH][U];  // 16 KB
    __shared__ __align__(16) float sbc[64];

    const int tid  = threadIdx.x;
    const int wid  = tid >> 6;          // 0: chain, 1: px b0, 2: px b1
    const int lane = tid & 63;
    const int v    = lane & 31;
    const int h    = lane >> 5;         // batch half within the chain wave
    const int b0   = blockIdx.x * 2;

    if (wid == 0) {
        // ================= dual-chain wave =================
        float w2[U];
        #pragma unroll
        for (int i = 0; i < U; ++i) w2[i] = W2[i*U + v];
        const float b2v = b2[v];

        float state = 0.f, pool = 0.f;
        __syncthreads();                             // px[0] ready

        for (int c = 0; c < NCH; ++c) {
            const float* pxb = &pxring[c & 1][h][0][v];
            const float4* sb4 = (const float4*)(&sbc[h * 32]);
            #pragma unroll 8
            for (int s = 0; s < CH; ++s) {
                float px = pxb[s * U];               // ds_read_b32 (off-chain)
                sbc[lane] = state;                   // broadcast both chains' states
                float4 sbv[8];
                #pragma unroll
                for (int q = 0; q < 8; ++q) sbv[q] = sb4[q];   // 8x ds_read_b128
                float a0 = b2v, a1 = 0.f, a2 = 0.f, a3 = 0.f;
                #pragma unroll
                for (int q = 0; q < 8; ++q) {
                    a0 = fmaf(sbv[q].x, w2[4*q+0], a0);
                    a1 = fmaf(sbv[q].y, w2[4*q+1], a1);
                    a2 = fmaf(sbv[q].z, w2[4*q+2], a2);
                    a3 = fmaf(sbv[q].w, w2[4*q+3], a3);
                }
                float z = (a0 + a1) + (a2 + a3);
                state = px + tanh_fast(z);
                pool += state;
            }
            __syncthreads();
        }

        // epilogue: per-half reduce of pool * Wc
        float r = pool * Wc[v];
        r += __shfl_xor(r, 16);
        r += __shfl_xor(r, 8);
        r += __shfl_xor(r, 4);
        r += __shfl_xor(r, 2);
        r += __shfl_xor(r, 1);
        float res = r * (1.0f / TT) + bc[0];
        if (lane == 0)               out[b0]     = res;
        if (lane == 32 && b0+1 < B)  out[b0 + 1] = res;
    } else {
        // ================= px producer waves =================
        const int bl = wid - 1;                      // my batch within the pair
        int bb = b0 + bl; if (bb >= B) bb = B - 1;   // defensive clamp
        float w1[U];
        #pragma unroll
        for (int i = 0; i < U; ++i) w1[i] = W1[i*U + v];
        const float b1v = b1[v];
        const float* xsrc = x + (size_t)bb * TT * U;

        const int th = h;                            // t-parity handled per half

        // ---- prologue: stage chunks 0,1 ; compute px[0] ----
        #pragma unroll
        for (int q = 0; q < 4; ++q)
            __builtin_amdgcn_global_load_lds(
                (const __attribute__((address_space(1))) void*)(xsrc + q*256 + lane*4),
                (__attribute__((address_space(3))) void*)(&xring[0][bl][0][0] + q*256),
                16, 0, 0);
        #pragma unroll
        for (int q = 0; q < 4; ++q)
            __builtin_amdgcn_global_load_lds(
                (const __attribute__((address_space(1))) void*)(xsrc + CH*U + q*256 + lane*4),
                (__attribute__((address_space(3))) void*)(&xring[1][bl][0][0] + q*256),
                16, 0, 0);
        asm volatile("s_waitcnt vmcnt(4)" ::: "memory");   // chunk 0 landed
        {
            const float* xs = &xring[0][bl][0][0];
            float* pxd = &pxring[0][bl][0][0];
            #pragma unroll 4
            for (int it = 0; it < CH/2; ++it) {
                const int t = it*2 + th;
                const float4* xr = (const float4*)(xs + t*U);
                float4 xv[8];
                #pragma unroll
                for (int q = 0; q < 8; ++q) xv[q] = xr[q];
                float a0 = b1v, a1 = 0.f, a2 = 0.f, a3 = 0.f;
                #pragma unroll
                for (int q = 0; q < 8; ++q) {
                    a0 = fmaf(xv[q].x, w1[4*q+0], a0);
                    a1 = fmaf(xv[q].y, w1[4*q+1], a1);
                    a2 = fmaf(xv[q].z, w1[4*q+2], a2);
                    a3 = fmaf(xv[q].w, w1[4*q+3], a3);
                }
                pxd[t*U + v] = tanh_fast((a0 + a1) + (a2 + a3));
            }
        }
        __syncthreads();

        // ---- main loop ----
        for (int c = 0; c < NCH; ++c) {
            int cs = (c + 2 < NCH) ? c + 2 : NCH - 1;        // clamped dummy at tail
            const float* sbase = xsrc + (size_t)cs * CH * U;
            float*       dbase = &xring[c & 1][bl][0][0];
            #pragma unroll
            for (int q = 0; q < 4; ++q)
                __builtin_amdgcn_global_load_lds(
                    (const __attribute__((address_space(1))) void*)(sbase + q*256 + lane*4),
                    (__attribute__((address_space(3))) void*)(dbase + q*256),
                    16, 0, 0);
            asm volatile("s_waitcnt vmcnt(4)" ::: "memory"); // chunk c+1 landed
            if (c + 1 < NCH) {
                const float* xs = &xring[(c+1) & 1][bl][0][0];
                float* pxd = &pxring[(c+1) & 1][bl][0][0];
                #pragma unroll 4
                for (int it = 0; it < CH/2; ++it) {
                    const int t = it*2 + th;
                    const float4* xr = (const float4*)(xs + t*U);
                    float4 xv[8];
                    #pragma unroll
                    for (int q = 0; q < 8; ++q) xv[q] = xr[q];
                    float a0 = b1v, a1 = 0.f, a2 = 0.f, a3 = 0.f;
                    #pragma unroll
                    for (int q = 0; q < 8; ++q) {
                        a0 = fmaf(xv[q].x, w1[4*q+0], a0);
                        a1 = fmaf(xv[q].y, w1[4*q+1], a1);
                        a2 = fmaf(xv[q].z, w1[4*q+2], a2);
                        a3 = fmaf(xv[q].w, w1[4*q+3], a3);
                    }
                    pxd[t*U + v] = tanh_fast((a0 + a1) + (a2 + a3));
                }
            }
            __syncthreads();
        }
    }
}

extern "C" void kernel_launch(void* const* d_in, const int* in_sizes, int n_in,
                              void* d_out, int out_size, void* d_ws, size_t ws_size,
                              hipStream_t stream) {
    const float* x  = (const float*)d_in[0];
    const float* W1 = (const float*)d_in[1];
    const float* b1 = (const float*)d_in[2];
    const float* W2 = (const float*)d_in[3];
    const float* b2 = (const float*)d_in[4];
    const float* Wc = (const float*)d_in[5];
    const float* bc = (const float*)d_in[6];
    float* out = (float*)d_out;

    const int B = out_size;              // 256
    const int nblk = (B + 1) / 2;        // 2 batches per block
    rnn_fused<<<nblk, 192, 0, stream>>>(x, W1, b1, W2, b2, Wc, bc, out, B);
}

// Round 5
// 500.613 us; speedup vs baseline: 2.9693x; 1.1721x over previous
//
#include <hip/hip_runtime.h>

#define TT  4096
#define U   32
#define CH  32              // timesteps per chunk
#define NCH (TT/CH)         // 128 chunks
#define TP  36              // padded pxT row stride (floats): 144B rows, 16B-aligned

// tanh(z + b) = 1 - 2/(1 + 2^(z*c + b*c)),  c = 2*log2(e)
__device__ __forceinline__ float tanh_fast_pre(float z, float bpre) {
    float t = __builtin_amdgcn_exp2f(fmaf(z, 2.885390081777927f, bpre));
    return fmaf(-2.0f, __builtin_amdgcn_rcpf(t + 1.0f), 1.0f);
}
// plain tanh(z) with bias already folded into z
__device__ __forceinline__ float tanh_fast(float z) {
    float t = __builtin_amdgcn_exp2f(z * 2.885390081777927f);
    return fmaf(-2.0f, __builtin_amdgcn_rcpf(t + 1.0f), 1.0f);
}

__global__ __launch_bounds__(128, 1)
void rnn_fused(const float* __restrict__ x,  const float* __restrict__ W1,
               const float* __restrict__ b1, const float* __restrict__ W2,
               const float* __restrict__ b2, const float* __restrict__ Wc,
               const float* __restrict__ bc, float* __restrict__ out, int B)
{
    __shared__ __align__(16) float xring[2][CH][U];   // 8 KB  x staging ring
    __shared__ __align__(16) float pxT[2][U][TP];     // 9 KB  transposed px ring

    const int tid  = threadIdx.x;
    const int wid  = tid >> 6;          // 0: chain wave, 1: px producer wave
    const int lane = tid & 63;
    const int v    = lane & 31;
    const int kh   = lane >> 5;
    const int b    = blockIdx.x;

    if (wid == 0) {
        // ========================= chain wave =========================
        float w2[U];
        #pragma unroll
        for (int i = 0; i < U; ++i) w2[i] = W2[i*U + v];
        const float b2pre = b2[v] * 2.885390081777927f;

        __builtin_amdgcn_s_setprio(1);   // favor the critical-path wave

        float state = 0.f, pool = 0.f;

        #define RL(K) __uint_as_float(__builtin_amdgcn_readlane(__float_as_uint(state), (K)))
        auto step = [&](float px) {
            float a0 = RL(0) * w2[0];
            float a1 = RL(1) * w2[1];
            float a2 = RL(2) * w2[2];
            float a3 = RL(3) * w2[3];
            #pragma unroll
            for (int k = 4; k < 32; k += 4) {
                a0 = fmaf(RL(k+0), w2[k+0], a0);
                a1 = fmaf(RL(k+1), w2[k+1], a1);
                a2 = fmaf(RL(k+2), w2[k+2], a2);
                a3 = fmaf(RL(k+3), w2[k+3], a3);
            }
            float z = (a0 + a1) + (a2 + a3);
            float h = tanh_fast_pre(z, b2pre);
            state = px + h;
            pool += state;
        };

        __syncthreads();                 // pxT[0] ready

        for (int c = 0; c < NCH; ++c) {
            const float4* pxq = (const float4*)&pxT[c & 1][v][0];  // 8x float4 = 32 steps
            float4 pa = pxq[0];
            // hand-unrolled ping-pong: prefetch next quad while stepping current
            float4 pb = pxq[1];
            step(pa.x); step(pa.y); step(pa.z); step(pa.w);
            pa = pxq[2];
            step(pb.x); step(pb.y); step(pb.z); step(pb.w);
            pb = pxq[3];
            step(pa.x); step(pa.y); step(pa.z); step(pa.w);
            pa = pxq[4];
            step(pb.x); step(pb.y); step(pb.z); step(pb.w);
            pb = pxq[5];
            step(pa.x); step(pa.y); step(pa.z); step(pa.w);
            pa = pxq[6];
            step(pb.x); step(pb.y); step(pb.z); step(pb.w);
            pb = pxq[7];
            step(pa.x); step(pa.y); step(pa.z); step(pa.w);
            step(pb.x); step(pb.y); step(pb.z); step(pb.w);
            __syncthreads();
        }
        #undef RL

        // epilogue: pooled dot with Wc (state/pool replicated across halves)
        float r = pool * Wc[v];
        r += __shfl_xor(r, 16);
        r += __shfl_xor(r, 8);
        r += __shfl_xor(r, 4);
        r += __shfl_xor(r, 2);
        r += __shfl_xor(r, 1);
        if (lane == 0) out[b] = r * (1.0f / TT) + bc[0];
    } else {
        // ======================= px producer wave =======================
        float w1[U];
        #pragma unroll
        for (int i = 0; i < U; ++i) w1[i] = W1[i*U + v];
        const float b1v = b1[v];
        const float* xsrc = x + (size_t)b * TT * U;

        // compute px for all 32 t of chunk `cc` (in xring[cc&1]) into pxT[cc&1]
        auto produce = [&](int cc) {
            const float* xs = &xring[cc & 1][0][0];
            float* pxd = &pxT[cc & 1][v][0];
            #pragma unroll 4
            for (int it = 0; it < CH/2; ++it) {
                const int t = it*2 + kh;              // halves cover even/odd t
                const float4* xr = (const float4*)(xs + t*U);
                float4 xv0 = xr[0], xv1 = xr[1], xv2 = xr[2], xv3 = xr[3];
                float4 xv4 = xr[4], xv5 = xr[5], xv6 = xr[6], xv7 = xr[7];
                float a0 = fmaf(xv0.x, w1[0],  b1v);
                float a1 = xv0.y * w1[1];
                float a2 = xv0.z * w1[2];
                float a3 = xv0.w * w1[3];
                a0 = fmaf(xv1.x, w1[4],  a0); a1 = fmaf(xv1.y, w1[5],  a1);
                a2 = fmaf(xv1.z, w1[6],  a2); a3 = fmaf(xv1.w, w1[7],  a3);
                a0 = fmaf(xv2.x, w1[8],  a0); a1 = fmaf(xv2.y, w1[9],  a1);
                a2 = fmaf(xv2.z, w1[10], a2); a3 = fmaf(xv2.w, w1[11], a3);
                a0 = fmaf(xv3.x, w1[12], a0); a1 = fmaf(xv3.y, w1[13], a1);
                a2 = fmaf(xv3.z, w1[14], a2); a3 = fmaf(xv3.w, w1[15], a3);
                a0 = fmaf(xv4.x, w1[16], a0); a1 = fmaf(xv4.y, w1[17], a1);
                a2 = fmaf(xv4.z, w1[18], a2); a3 = fmaf(xv4.w, w1[19], a3);
                a0 = fmaf(xv5.x, w1[20], a0); a1 = fmaf(xv5.y, w1[21], a1);
                a2 = fmaf(xv5.z, w1[22], a2); a3 = fmaf(xv5.w, w1[23], a3);
                a0 = fmaf(xv6.x, w1[24], a0); a1 = fmaf(xv6.y, w1[25], a1);
                a2 = fmaf(xv6.z, w1[26], a2); a3 = fmaf(xv6.w, w1[27], a3);
                a0 = fmaf(xv7.x, w1[28], a0); a1 = fmaf(xv7.y, w1[29], a1);
                a2 = fmaf(xv7.z, w1[30], a2); a3 = fmaf(xv7.w, w1[31], a3);
                pxd[t] = tanh_fast((a0 + a1) + (a2 + a3));   // pxT[slot][v][t]
            }
        };

        auto stage = [&](int chunk, int slot) {
            const float* sbase = xsrc + (size_t)chunk * CH * U;
            float*       dbase = &xring[slot][0][0];
            #pragma unroll
            for (int q = 0; q < 4; ++q)
                __builtin_amdgcn_global_load_lds(
                    (const __attribute__((address_space(1))) void*)(sbase + q*256 + lane*4),
                    (__attribute__((address_space(3))) void*)(dbase + q*256),
                    16, 0, 0);
        };

        // prologue: stage chunks 0,1; compute px(0)
        stage(0, 0);
        stage(1, 1);
        asm volatile("s_waitcnt vmcnt(4)" ::: "memory");   // chunk 0 landed
        __builtin_amdgcn_sched_barrier(0);
        produce(0);
        __syncthreads();

        for (int c = 0; c < NCH; ++c) {
            int cs = (c + 2 < NCH) ? c + 2 : NCH - 1;      // clamped dummy at tail
            stage(cs, c & 1);
            asm volatile("s_waitcnt vmcnt(4)" ::: "memory"); // chunk c+1 landed
            __builtin_amdgcn_sched_barrier(0);
            if (c + 1 < NCH) produce(c + 1);
            __syncthreads();
        }
    }
}

extern "C" void kernel_launch(void* const* d_in, const int* in_sizes, int n_in,
                              void* d_out, int out_size, void* d_ws, size_t ws_size,
                              hipStream_t stream) {
    const float* x  = (const float*)d_in[0];
    const float* W1 = (const float*)d_in[1];
    const float* b1 = (const float*)d_in[2];
    const float* W2 = (const float*)d_in[3];
    const float* b2 = (const float*)d_in[4];
    const float* Wc = (const float*)d_in[5];
    const float* bc = (const float*)d_in[6];
    float* out = (float*)d_out;

    const int B = out_size;              // 256
    rnn_fused<<<B, 128, 0, stream>>>(x, W1, b1, W2, b2, Wc, bc, out, B);
}

// Round 6
// 249.725 us; speedup vs baseline: 5.9525x; 2.0047x over previous
//
#include <hip/hip_runtime.h>

#define TT    4096
#define U     32
#define CH    32                     // timesteps per chunk
#define NSEG  8                      // segments per batch (one chain wave each)
#define SEGLEN (TT/NSEG)             // 512
#define WARMC 4                      // warm-up chunks = 128 steps
#define NCHK  (SEGLEN/CH + WARMC)    // 20 chunks per segment
#define TP    36                     // padded pxT row stride (floats)

#define CLOG2E 2.885390081777927f    // 2*log2(e)

__global__ __launch_bounds__(768, 1)
void rnn_fused(const float* __restrict__ x,  const float* __restrict__ W1,
               const float* __restrict__ b1, const float* __restrict__ W2,
               const float* __restrict__ b2, const float* __restrict__ Wc,
               const float* __restrict__ bc, float* __restrict__ out, int B)
{
    __shared__ __align__(16) float xring[NSEG][2][CH][U];   // 32 KB
    __shared__ __align__(16) float pxT[NSEG][2][U][TP];     // 73.7 KB (holds px+1)
    __shared__ float part[NSEG];

    const int tid  = threadIdx.x;
    const int wid  = tid >> 6;          // 0..7 chain (segment), 8..11 producer
    const int lane = tid & 63;
    const int v    = lane & 31;
    const int kh   = lane >> 5;
    const int b    = blockIdx.x;

    if (wid < NSEG) {
        // ===================== chain wave, segment s =====================
        const int s = wid;
        float w2s[U];
        #pragma unroll
        for (int i = 0; i < U; ++i) w2s[i] = W2[i*U + v] * CLOG2E;
        const float b2pre = b2[v] * CLOG2E;

        __builtin_amdgcn_s_setprio(1);
        float state = 0.f, pool = 0.f;
        __syncthreads();                       // chunk-0 px ready

        #define RL(K) __uint_as_float(__builtin_amdgcn_readlane(__float_as_uint(state), (K)))
        for (int c = 0; c < NCHK; ++c) {
            if (s > 0 || c >= WARMC) {         // seg 0 has no warm-up phase
                const float pm = (c >= WARMC) ? 1.f : 0.f;
                const float4* pxq = (const float4*)&pxT[s][c & 1][v][0];
                auto step = [&](float px1) {
                    float a0 = fmaf(RL(0), w2s[0], b2pre);
                    float a1 = RL(1) * w2s[1];
                    float a2 = RL(2) * w2s[2];
                    float a3 = RL(3) * w2s[3];
                    #pragma unroll
                    for (int k = 4; k < 32; k += 4) {
                        a0 = fmaf(RL(k+0), w2s[k+0], a0);
                        a1 = fmaf(RL(k+1), w2s[k+1], a1);
                        a2 = fmaf(RL(k+2), w2s[k+2], a2);
                        a3 = fmaf(RL(k+3), w2s[k+3], a3);
                    }
                    float zs = (a0 + a1) + (a2 + a3);          // already ×2log2e, +b2
                    float t  = __builtin_amdgcn_exp2f(zs);
                    float r  = __builtin_amdgcn_rcpf(t + 1.0f);
                    state = fmaf(-2.0f, r, px1);               // px+1 + tanh-1 form
                    pool  = fmaf(state, pm, pool);
                };
                float4 pa = pxq[0];
                float4 pb = pxq[1];
                step(pa.x); step(pa.y); step(pa.z); step(pa.w);
                pa = pxq[2];
                step(pb.x); step(pb.y); step(pb.z); step(pb.w);
                pb = pxq[3];
                step(pa.x); step(pa.y); step(pa.z); step(pa.w);
                pa = pxq[4];
                step(pb.x); step(pb.y); step(pb.z); step(pb.w);
                pb = pxq[5];
                step(pa.x); step(pa.y); step(pa.z); step(pa.w);
                pa = pxq[6];
                step(pb.x); step(pb.y); step(pb.z); step(pb.w);
                pb = pxq[7];
                step(pa.x); step(pa.y); step(pa.z); step(pa.w);
                step(pb.x); step(pb.y); step(pb.z); step(pb.w);
            }
            __syncthreads();
        }
        #undef RL

        // per-segment partial of pooled dot with Wc
        float r = pool * Wc[v];
        r += __shfl_xor(r, 16);
        r += __shfl_xor(r, 8);
        r += __shfl_xor(r, 4);
        r += __shfl_xor(r, 2);
        r += __shfl_xor(r, 1);
        if (lane == 0) part[s] = r;
        __syncthreads();
        if (tid == 0) {
            float acc = 0.f;
            #pragma unroll
            for (int i = 0; i < NSEG; ++i) acc += part[i];
            out[b] = acc * (1.0f / TT) + bc[0];
        }
    } else {
        // ================== producer wave p: segments 2p, 2p+1 ==================
        const int p  = wid - NSEG;           // 0..3
        const int sA = 2*p, sB = 2*p + 1;
        float w1s[U];
        #pragma unroll
        for (int i = 0; i < U; ++i) w1s[i] = W1[i*U + v] * CLOG2E;
        const float b1pre = b1[v] * CLOG2E;
        const float* xb = x + (size_t)b * TT * U;

        auto stage = [&](int seg, int cc) {    // stage chunk cc of segment seg
            const int t0 = seg*SEGLEN - WARMC*CH + cc*CH;   // global row of chunk start
            float* dst = &xring[seg][cc & 1][0][0];
            #pragma unroll
            for (int q = 0; q < 4; ++q) {
                int row = t0 + q*8 + (lane >> 3);
                row = row < 0 ? 0 : (row >= TT ? TT-1 : row);   // clamp OOB (warm/tail)
                const float* src = xb + (size_t)row*U + (lane & 7)*4;
                __builtin_amdgcn_global_load_lds(
                    (const __attribute__((address_space(1))) void*)src,
                    (__attribute__((address_space(3))) void*)(dst + q*256),
                    16, 0, 0);
            }
        };
        auto produce = [&](int seg, int cc) {  // px+1 for chunk cc into pxT
            const float* xs = &xring[seg][cc & 1][0][0];
            float* pxd = &pxT[seg][cc & 1][v][0];
            #pragma unroll 4
            for (int it = 0; it < CH/2; ++it) {
                const int tl = it*2 + kh;                      // halves: even/odd rows
                const float4* xr = (const float4*)(xs + tl*U);
                float4 x0 = xr[0], x1 = xr[1], x2 = xr[2], x3 = xr[3];
                float4 x4 = xr[4], x5 = xr[5], x6 = xr[6], x7 = xr[7];
                float a0 = fmaf(x0.x, w1s[0], b1pre);
                float a1 = x0.y * w1s[1];
                float a2 = x0.z * w1s[2];
                float a3 = x0.w * w1s[3];
                a0 = fmaf(x1.x, w1s[4],  a0); a1 = fmaf(x1.y, w1s[5],  a1);
                a2 = fmaf(x1.z, w1s[6],  a2); a3 = fmaf(x1.w, w1s[7],  a3);
                a0 = fmaf(x2.x, w1s[8],  a0); a1 = fmaf(x2.y, w1s[9],  a1);
                a2 = fmaf(x2.z, w1s[10], a2); a3 = fmaf(x2.w, w1s[11], a3);
                a0 = fmaf(x3.x, w1s[12], a0); a1 = fmaf(x3.y, w1s[13], a1);
                a2 = fmaf(x3.z, w1s[14], a2); a3 = fmaf(x3.w, w1s[15], a3);
                a0 = fmaf(x4.x, w1s[16], a0); a1 = fmaf(x4.y, w1s[17], a1);
                a2 = fmaf(x4.z, w1s[18], a2); a3 = fmaf(x4.w, w1s[19], a3);
                a0 = fmaf(x5.x, w1s[20], a0); a1 = fmaf(x5.y, w1s[21], a1);
                a2 = fmaf(x5.z, w1s[22], a2); a3 = fmaf(x5.w, w1s[23], a3);
                a0 = fmaf(x6.x, w1s[24], a0); a1 = fmaf(x6.y, w1s[25], a1);
                a2 = fmaf(x6.z, w1s[26], a2); a3 = fmaf(x6.w, w1s[27], a3);
                a0 = fmaf(x7.x, w1s[28], a0); a1 = fmaf(x7.y, w1s[29], a1);
                a2 = fmaf(x7.z, w1s[30], a2); a3 = fmaf(x7.w, w1s[31], a3);
                float zs = (a0 + a1) + (a2 + a3);
                float t  = __builtin_amdgcn_exp2f(zs);
                float r  = __builtin_amdgcn_rcpf(t + 1.0f);
                pxd[tl] = fmaf(-2.0f, r, 2.0f);                // px + 1
            }
        };

        // prologue: stage chunks 0,1 of both segments; produce chunk 0
        stage(sA, 0); stage(sB, 0);
        stage(sA, 1); stage(sB, 1);
        asm volatile("s_waitcnt vmcnt(8)" ::: "memory");       // chunk-0 pair landed
        __builtin_amdgcn_sched_barrier(0);
        if (sA != 0) produce(sA, 0);     // seg0 warm chunks are never consumed
        produce(sB, 0);
        __syncthreads();

        for (int c = 0; c < NCHK; ++c) {
            // stage chunk c+2 (dead slot (c+2)&1; OOB rows clamp -> harmless)
            stage(sA, c + 2);
            stage(sB, c + 2);
            asm volatile("s_waitcnt vmcnt(8)" ::: "memory");   // chunk c+1 pair landed
            __builtin_amdgcn_sched_barrier(0);
            if (c + 1 < NCHK) {
                if (!(sA == 0 && c + 1 < WARMC)) produce(sA, c + 1);
                produce(sB, c + 1);
            }
            __syncthreads();
        }
        __syncthreads();                 // match chains' epilogue barrier
    }
}

extern "C" void kernel_launch(void* const* d_in, const int* in_sizes, int n_in,
                              void* d_out, int out_size, void* d_ws, size_t ws_size,
                              hipStream_t stream) {
    const float* x  = (const float*)d_in[0];
    const float* W1 = (const float*)d_in[1];
    const float* b1 = (const float*)d_in[2];
    const float* W2 = (const float*)d_in[3];
    const float* b2 = (const float*)d_in[4];
    const float* Wc = (const float*)d_in[5];
    const float* bc = (const float*)d_in[6];
    float* out = (float*)d_out;

    const int B = out_size;              // 256
    rnn_fused<<<B, 768, 0, stream>>>(x, W1, b1, W2, b2, Wc, bc, out, B);
}

// Round 7
// 167.350 us; speedup vs baseline: 8.8825x; 1.4922x over previous
//
#include <hip/hip_runtime.h>

#define TT    4096
#define U     32
#define CH    32                     // timesteps per chunk
#define NSEG  8                      // segments per batch (2 per chain wave)
#define SEGLEN (TT/NSEG)             // 512
#define WARMC 4                      // warm-up chunks = 128 steps
#define NCHK  (SEGLEN/CH + WARMC)    // 20 chunks per segment
#define TP    36                     // padded pxT row stride (floats)

#define CLOG2E 2.885390081777927f    // 2*log2(e)

__global__ __launch_bounds__(512, 1)
void rnn_fused(const float* __restrict__ x,  const float* __restrict__ W1,
               const float* __restrict__ b1, const float* __restrict__ W2,
               const float* __restrict__ b2, const float* __restrict__ Wc,
               const float* __restrict__ bc, float* __restrict__ out, int B)
{
    __shared__ __align__(16) float xring[NSEG][2][CH][U];   // 64 KB
    __shared__ __align__(16) float pxT[NSEG][2][U][TP];     // 73.7 KB (holds px+1)
    __shared__ __align__(16) float sbc[4][64];              // per-chain-wave state bcast
    __shared__ float part[NSEG];

    const int tid  = threadIdx.x;
    const int wid  = tid >> 6;          // 0..3 chain waves, 4..7 producer waves
    const int lane = tid & 63;
    const int v    = lane & 31;
    const int h    = lane >> 5;         // half: which of the wave's 2 segments
    const int b    = blockIdx.x;

    if (wid < 4) {
        // ============ chain wave: segment 2*wid + h per half ============
        const int seg = 2*wid + h;
        float w2s[U];
        #pragma unroll
        for (int i = 0; i < U; ++i) w2s[i] = W2[i*U + v] * CLOG2E;
        const float b2pre = b2[v] * CLOG2E;
        // seg 0 has no true pre-history: zero its state at the warm/real boundary
        const float zm = (wid == 0 && h == 0) ? 0.f : 1.f;

        float* sbw = &sbc[wid][0];
        const float4* sb4 = (const float4*)&sbc[wid][h * 32];

        __builtin_amdgcn_s_setprio(1);
        float state = 0.f, pool = 0.f;
        __syncthreads();                       // chunk-0 px ready

        for (int c = 0; c < NCHK; ++c) {
            if (c == WARMC) { state *= zm; pool = 0.f; }
            const float4* pxq = (const float4*)&pxT[seg][c & 1][v][0];
            auto step = [&](float px1) {
                sbw[lane] = state;             // both halves publish their chains
                float4 s0 = sb4[0], s1 = sb4[1], s2 = sb4[2], s3 = sb4[3];
                float4 s4 = sb4[4], s5 = sb4[5], s6 = sb4[6], s7 = sb4[7];
                float a0 = fmaf(s0.x, w2s[0], b2pre);
                float a1 = s0.y * w2s[1];
                float a2 = s0.z * w2s[2];
                float a3 = s0.w * w2s[3];
                a0 = fmaf(s1.x, w2s[4],  a0); a1 = fmaf(s1.y, w2s[5],  a1);
                a2 = fmaf(s1.z, w2s[6],  a2); a3 = fmaf(s1.w, w2s[7],  a3);
                a0 = fmaf(s2.x, w2s[8],  a0); a1 = fmaf(s2.y, w2s[9],  a1);
                a2 = fmaf(s2.z, w2s[10], a2); a3 = fmaf(s2.w, w2s[11], a3);
                a0 = fmaf(s3.x, w2s[12], a0); a1 = fmaf(s3.y, w2s[13], a1);
                a2 = fmaf(s3.z, w2s[14], a2); a3 = fmaf(s3.w, w2s[15], a3);
                a0 = fmaf(s4.x, w2s[16], a0); a1 = fmaf(s4.y, w2s[17], a1);
                a2 = fmaf(s4.z, w2s[18], a2); a3 = fmaf(s4.w, w2s[19], a3);
                a0 = fmaf(s5.x, w2s[20], a0); a1 = fmaf(s5.y, w2s[21], a1);
                a2 = fmaf(s5.z, w2s[22], a2); a3 = fmaf(s5.w, w2s[23], a3);
                a0 = fmaf(s6.x, w2s[24], a0); a1 = fmaf(s6.y, w2s[25], a1);
                a2 = fmaf(s6.z, w2s[26], a2); a3 = fmaf(s6.w, w2s[27], a3);
                a0 = fmaf(s7.x, w2s[28], a0); a1 = fmaf(s7.y, w2s[29], a1);
                a2 = fmaf(s7.z, w2s[30], a2); a3 = fmaf(s7.w, w2s[31], a3);
                float zs = (a0 + a1) + (a2 + a3);          // prescaled, +b2 folded
                float t  = __builtin_amdgcn_exp2f(zs);
                float r  = __builtin_amdgcn_rcpf(t + 1.0f);
                state = fmaf(-2.0f, r, px1);               // px+1 + (tanh-1)
                pool += state;
            };
            float4 pa = pxq[0];
            float4 pb = pxq[1];
            step(pa.x); step(pa.y); step(pa.z); step(pa.w);
            pa = pxq[2];
            step(pb.x); step(pb.y); step(pb.z); step(pb.w);
            pb = pxq[3];
            step(pa.x); step(pa.y); step(pa.z); step(pa.w);
            pa = pxq[4];
            step(pb.x); step(pb.y); step(pb.z); step(pb.w);
            pb = pxq[5];
            step(pa.x); step(pa.y); step(pa.z); step(pa.w);
            pa = pxq[6];
            step(pb.x); step(pb.y); step(pb.z); step(pb.w);
            pb = pxq[7];
            step(pa.x); step(pa.y); step(pa.z); step(pa.w);
            step(pb.x); step(pb.y); step(pb.z); step(pb.w);
            __syncthreads();
        }

        // per-segment partial of pooled dot with Wc (reduce within each half)
        float r = pool * Wc[v];
        r += __shfl_xor(r, 16);
        r += __shfl_xor(r, 8);
        r += __shfl_xor(r, 4);
        r += __shfl_xor(r, 2);
        r += __shfl_xor(r, 1);
        if (v == 0) part[seg] = r;            // lanes 0 and 32
        __syncthreads();
        if (tid == 0) {
            float acc = 0.f;
            #pragma unroll
            for (int i = 0; i < NSEG; ++i) acc += part[i];
            out[b] = acc * (1.0f / TT) + bc[0];
        }
    } else {
        // ============ producer wave p: segments 2p, 2p+1 ============
        const int p  = wid - 4;
        const int sA = 2*p, sB = 2*p + 1;
        float w1s[U];
        #pragma unroll
        for (int i = 0; i < U; ++i) w1s[i] = W1[i*U + v] * CLOG2E;
        const float b1pre = b1[v] * CLOG2E;
        const float* xb = x + (size_t)b * TT * U;

        auto stage = [&](int seg, int cc) {    // stage chunk cc of segment seg
            const int t0 = seg*SEGLEN - WARMC*CH + cc*CH;
            float* dst = &xring[seg][cc & 1][0][0];
            #pragma unroll
            for (int q = 0; q < 4; ++q) {
                int row = t0 + q*8 + (lane >> 3);
                row = row < 0 ? 0 : (row >= TT ? TT-1 : row);   // clamp OOB
                const float* src = xb + (size_t)row*U + (lane & 7)*4;
                __builtin_amdgcn_global_load_lds(
                    (const __attribute__((address_space(1))) void*)src,
                    (__attribute__((address_space(3))) void*)(dst + q*256),
                    16, 0, 0);
            }
        };
        auto produce = [&](int seg, int cc) {  // px+1 for chunk cc into pxT
            const float* xs = &xring[seg][cc & 1][0][0];
            float* pxd = &pxT[seg][cc & 1][v][0];
            #pragma unroll 4
            for (int it = 0; it < CH/2; ++it) {
                const int tl = it*2 + h;                       // halves: even/odd rows
                const float4* xr = (const float4*)(xs + tl*U);
                float4 x0 = xr[0], x1 = xr[1], x2 = xr[2], x3 = xr[3];
                float4 x4 = xr[4], x5 = xr[5], x6 = xr[6], x7 = xr[7];
                float a0 = fmaf(x0.x, w1s[0], b1pre);
                float a1 = x0.y * w1s[1];
                float a2 = x0.z * w1s[2];
                float a3 = x0.w * w1s[3];
                a0 = fmaf(x1.x, w1s[4],  a0); a1 = fmaf(x1.y, w1s[5],  a1);
                a2 = fmaf(x1.z, w1s[6],  a2); a3 = fmaf(x1.w, w1s[7],  a3);
                a0 = fmaf(x2.x, w1s[8],  a0); a1 = fmaf(x2.y, w1s[9],  a1);
                a2 = fmaf(x2.z, w1s[10], a2); a3 = fmaf(x2.w, w1s[11], a3);
                a0 = fmaf(x3.x, w1s[12], a0); a1 = fmaf(x3.y, w1s[13], a1);
                a2 = fmaf(x3.z, w1s[14], a2); a3 = fmaf(x3.w, w1s[15], a3);
                a0 = fmaf(x4.x, w1s[16], a0); a1 = fmaf(x4.y, w1s[17], a1);
                a2 = fmaf(x4.z, w1s[18], a2); a3 = fmaf(x4.w, w1s[19], a3);
                a0 = fmaf(x5.x, w1s[20], a0); a1 = fmaf(x5.y, w1s[21], a1);
                a2 = fmaf(x5.z, w1s[22], a2); a3 = fmaf(x5.w, w1s[23], a3);
                a0 = fmaf(x6.x, w1s[24], a0); a1 = fmaf(x6.y, w1s[25], a1);
                a2 = fmaf(x6.z, w1s[26], a2); a3 = fmaf(x6.w, w1s[27], a3);
                a0 = fmaf(x7.x, w1s[28], a0); a1 = fmaf(x7.y, w1s[29], a1);
                a2 = fmaf(x7.z, w1s[30], a2); a3 = fmaf(x7.w, w1s[31], a3);
                float zs = (a0 + a1) + (a2 + a3);
                float t  = __builtin_amdgcn_exp2f(zs);
                float r  = __builtin_amdgcn_rcpf(t + 1.0f);
                pxd[tl] = fmaf(-2.0f, r, 2.0f);                // px + 1
            }
        };

        // prologue: stage chunks 0,1 of both segments; produce chunk 0
        stage(sA, 0); stage(sB, 0);
        stage(sA, 1); stage(sB, 1);
        asm volatile("s_waitcnt vmcnt(8)" ::: "memory");       // chunk-0 pair landed
        __builtin_amdgcn_sched_barrier(0);
        produce(sA, 0); produce(sB, 0);
        __syncthreads();

        for (int c = 0; c < NCHK; ++c) {
            stage(sA, c + 2);                  // slot (c+2)&1 == c&1 (already consumed)
            stage(sB, c + 2);
            asm volatile("s_waitcnt vmcnt(8)" ::: "memory");   // chunk c+1 pair landed
            __builtin_amdgcn_sched_barrier(0);
            if (c + 1 < NCHK) { produce(sA, c + 1); produce(sB, c + 1); }
            __syncthreads();
        }
        __syncthreads();                       // match chains' epilogue barrier
    }
}

extern "C" void kernel_launch(void* const* d_in, const int* in_sizes, int n_in,
                              void* d_out, int out_size, void* d_ws, size_t ws_size,
                              hipStream_t stream) {
    const float* x  = (const float*)d_in[0];
    const float* W1 = (const float*)d_in[1];
    const float* b1 = (const float*)d_in[2];
    const float* W2 = (const float*)d_in[3];
    const float* b2 = (const float*)d_in[4];
    const float* Wc = (const float*)d_in[5];
    const float* bc = (const float*)d_in[6];
    float* out = (float*)d_out;

    const int B = out_size;              // 256
    rnn_fused<<<B, 512, 0, stream>>>(x, W1, b1, W2, b2, Wc, bc, out, B);
}